// Round 6
// baseline (467.599 us; speedup 1.0000x reference)
//
#include <hip/hip_runtime.h>

#define LLEN 8192
#define CG 16
#define NG 512   // b(16) * GROUPS(32)

typedef float f32x4 __attribute__((ext_vector_type(4)));

__device__ __forceinline__ uint32_t bf16rne(float f) {
    uint32_t u = __float_as_uint(f);
    return (u + 0x7FFFu + ((u >> 16) & 1u)) >> 16;
}
__device__ __forceinline__ uint32_t packbf(float lo, float hi) {
    return bf16rne(lo) | (bf16rne(hi) << 16);
}
__device__ __forceinline__ float unlo(uint32_t p) { return __uint_as_float(p << 16); }
__device__ __forceinline__ float unhi(uint32_t p) { return __uint_as_float(p & 0xFFFF0000u); }

// One block per group; 1024 threads = 16 waves. x held in registers (bf16)
// between the sum pass and the apply pass -> zero HBM re-read.
// Wave w owns columns [512w, 512w+512): lane l holds cols 512w+4l..+3 (A)
// and 512w+256+4l..+3 (B) for all 16 rows.
__global__ __launch_bounds__(1024) void fused_kernel(const float* __restrict__ x,
                                                     const float* __restrict__ w1,
                                                     const float* __restrict__ b1,
                                                     const float* __restrict__ w3,
                                                     const float* __restrict__ b3,
                                                     float* __restrict__ out) {
    const int g    = blockIdx.x;
    const int wave = threadIdx.x >> 6;
    const int lane = threadIdx.x & 63;
    __shared__ float Spart[CG][CG];        // [wave][row] partial sums
    __shared__ float edgeL[CG][CG];        // x[row][512*wave]        (fp32)
    __shared__ float edgeR[CG][CG];        // x[row][512*wave + 511]  (fp32)
    __shared__ float V_lds[49];            // v0[0:16) v1[16:32) v2[32:48) cb

    const size_t rowbase = (size_t)g * CG * LLEN;
    const int colA = 512 * wave + 4 * lane;
    const int colB = colA + 256;

    // ---------------- phase 1: load, row-sum, pack to bf16 in regs ----------
    uint2 xA[CG], xB[CG];
    float rs[CG];
    #pragma unroll
    for (int i = 0; i < CG; ++i) {
        const float* rp = x + rowbase + (size_t)i * LLEN;
        float4 a = *reinterpret_cast<const float4*>(rp + colA);
        float4 b = *reinterpret_cast<const float4*>(rp + colB);
        rs[i] = (a.x + a.y) + (a.z + a.w) + (b.x + b.y) + (b.z + b.w);
        if (lane == 0)  edgeL[wave][i] = a.x;
        if (lane == 63) edgeR[wave][i] = b.w;
        xA[i].x = packbf(a.x, a.y);  xA[i].y = packbf(a.z, a.w);
        xB[i].x = packbf(b.x, b.y);  xB[i].y = packbf(b.z, b.w);
    }
    #pragma unroll
    for (int i = 0; i < CG; ++i) {
        float s = rs[i];
        #pragma unroll
        for (int off = 32; off; off >>= 1) s += __shfl_xor(s, off, 64);
        rs[i] = s;
    }
    if (lane < CG) Spart[wave][lane] = rs[lane];
    __syncthreads();

    // ---------------- prep: softmax -> collapsed taps (wave 0) ----------------
    if (wave == 0) {
        int i = lane & 15;
        float S = 0.f;
        #pragma unroll
        for (int w = 0; w < CG; ++w) S += Spart[w][i];
        float F = edgeL[0][i], L = edgeR[15][i];
        // broadcast all rows' S/F/L to lanes via shuffle over the 16-group
        const float invL = 1.0f / (float)LLEN;
        float s1 = 0.f, s2 = 0.f;
        #pragma unroll
        for (int k = 0; k < CG; ++k) {
            float Sk = __shfl(S, k, 16);
            float Fk = __shfl(F, k, 16);
            float Lk = __shfl(L, k, 16);
            s1 += w1[i * CG + k] * Sk;
            const float* w = &w3[(i * CG + k) * 3];
            s2 += w[0] * (Sk - Lk) + w[1] * Sk + w[2] * (Sk - Fk);
        }
        float m1 = s1 * invL + b1[i];
        float m2 = s2 * invL + b3[i];

        float mx1 = m1, mx2 = m2;
        #pragma unroll
        for (int off = 8; off; off >>= 1) {
            mx1 = fmaxf(mx1, __shfl_xor(mx1, off, 16));
            mx2 = fmaxf(mx2, __shfl_xor(mx2, off, 16));
        }
        float e1 = __expf(m1 - mx1), e2 = __expf(m2 - mx2);
        float d1 = e1, d2 = e2;
        #pragma unroll
        for (int off = 8; off; off >>= 1) {
            d1 += __shfl_xor(d1, off, 16);
            d2 += __shfl_xor(d2, off, 16);
        }
        float a1 = e1 / d1, a2 = e2 / d2;

        float cb = a1 * b3[i] + a2 * b1[i];
        #pragma unroll
        for (int off = 8; off; off >>= 1) cb += __shfl_xor(cb, off, 16);

        float v0 = 0.f, v1v = 0.f, v2 = 0.f;
        #pragma unroll
        for (int k = 0; k < CG; ++k) {
            float a1k = __shfl(a1, k, 16);
            float a2k = __shfl(a2, k, 16);
            const float* w = &w3[(k * CG + i) * 3];
            v0  += a1k * w[0];
            v1v += a1k * w[1] + a2k * w1[k * CG + i];
            v2  += a1k * w[2];
        }
        if (lane < 16) {
            V_lds[i]      = v0;
            V_lds[16 + i] = v1v;
            V_lds[32 + i] = v2;
            if (lane == 0) V_lds[48] = cb;
        }
    }
    __syncthreads();

    // ---------------- phase 2: 3-tap gate from registers ----------------
    const float cbv = V_lds[48];
    float wA0 = cbv, wA1 = cbv, wA2 = cbv, wA3 = cbv;
    float wB0 = cbv, wB1 = cbv, wB2 = cbv, wB3 = cbv;
    #pragma unroll
    for (int i = 0; i < CG; ++i) {
        float a0 = unlo(xA[i].x), a1e = unhi(xA[i].x);
        float a2e = unlo(xA[i].y), a3 = unhi(xA[i].y);
        float b0 = unlo(xB[i].x), b1e = unhi(xB[i].x);
        float b2e = unlo(xB[i].y), b3e = unhi(xB[i].y);

        float pA = __shfl_up(a3, 1, 64);
        float nA = __shfl_down(a0, 1, 64);
        float pB = __shfl_up(b3e, 1, 64);
        float nB = __shfl_down(b0, 1, 64);
        float b0l0  = __shfl(b0, 0, 64);
        float a3l63 = __shfl(a3, 63, 64);
        if (lane == 0)  pA = (wave > 0)  ? edgeR[wave - 1][i] : 0.f;
        if (lane == 63) nA = b0l0;
        if (lane == 0)  pB = a3l63;
        if (lane == 63) nB = (wave < 15) ? edgeL[wave + 1][i] : 0.f;

        const float v0 = V_lds[i], v1c = V_lds[16 + i], v2c = V_lds[32 + i];
        wA0 += v0 * pA  + v1c * a0  + v2c * a1e;
        wA1 += v0 * a0  + v1c * a1e + v2c * a2e;
        wA2 += v0 * a1e + v1c * a2e + v2c * a3;
        wA3 += v0 * a2e + v1c * a3  + v2c * nA;
        wB0 += v0 * pB  + v1c * b0  + v2c * b1e;
        wB1 += v0 * b0  + v1c * b1e + v2c * b2e;
        wB2 += v0 * b1e + v1c * b2e + v2c * b3e;
        wB3 += v0 * b2e + v1c * b3e + v2c * nB;
    }
    const float sA0 = 1.f / (1.f + __expf(-wA0));
    const float sA1 = 1.f / (1.f + __expf(-wA1));
    const float sA2 = 1.f / (1.f + __expf(-wA2));
    const float sA3 = 1.f / (1.f + __expf(-wA3));
    const float sB0 = 1.f / (1.f + __expf(-wB0));
    const float sB1 = 1.f / (1.f + __expf(-wB1));
    const float sB2 = 1.f / (1.f + __expf(-wB2));
    const float sB3 = 1.f / (1.f + __expf(-wB3));

    #pragma unroll
    for (int i = 0; i < CG; ++i) {
        float* rp = out + rowbase + (size_t)i * LLEN;
        f32x4 oa = { unlo(xA[i].x) * sA0, unhi(xA[i].x) * sA1,
                     unlo(xA[i].y) * sA2, unhi(xA[i].y) * sA3 };
        f32x4 ob = { unlo(xB[i].x) * sB0, unhi(xB[i].x) * sB1,
                     unlo(xB[i].y) * sB2, unhi(xB[i].y) * sB3 };
        *reinterpret_cast<f32x4*>(rp + colA) = oa;
        *reinterpret_cast<f32x4*>(rp + colB) = ob;
    }
}

extern "C" void kernel_launch(void* const* d_in, const int* in_sizes, int n_in,
                              void* d_out, int out_size, void* d_ws, size_t ws_size,
                              hipStream_t stream) {
    const float* x  = (const float*)d_in[0];
    const float* w1 = (const float*)d_in[1];
    const float* b1 = (const float*)d_in[2];
    const float* w3 = (const float*)d_in[3];
    const float* b3 = (const float*)d_in[4];
    float* out = (float*)d_out;

    fused_kernel<<<NG, 1024, 0, stream>>>(x, w1, b1, w3, b3, out);
}

// Round 7
// 381.317 us; speedup vs baseline: 1.2263x; 1.2263x over previous
//
#include <hip/hip_runtime.h>

#define LLEN 8192
#define CG 16
#define NG 512   // b(16) * GROUPS(32)

typedef float f32x4 __attribute__((ext_vector_type(4)));

__device__ __forceinline__ uint32_t bf16rne(float f) {
    uint32_t u = __float_as_uint(f);
    return (u + 0x7FFFu + ((u >> 16) & 1u)) >> 16;
}
__device__ __forceinline__ uint32_t packbf(float lo, float hi) {
    return bf16rne(lo) | (bf16rne(hi) << 16);
}
__device__ __forceinline__ float unlo(uint32_t p) { return __uint_as_float(p << 16); }
__device__ __forceinline__ float unhi(uint32_t p) { return __uint_as_float(p & 0xFFFF0000u); }

#define XB_U32 2048                        // u32 per LDS row (4096 bf16 cols)
#define LDS_XB_BYTES (CG * XB_U32 * 4)     // 131072
#define LDS_TOTAL (LDS_XB_BYTES + (256 + 256 + 256 + 16 + 16 + 49) * 4)

// One block per group; 1024 threads = 16 waves; 1 block/CU (128 KiB LDS).
// Cols [0,4096) live in registers as packed bf16 (32 u32/lane);
// cols [4096,8192) live in LDS as packed bf16. Zero HBM re-read of x.
// Wave w owns reg-cols [256w,256w+256) and LDS-cols [4096+256w, +256).
extern "C" __global__ __launch_bounds__(1024, 4) void fused_kernel(
        const float* __restrict__ x,  const float* __restrict__ w1,
        const float* __restrict__ b1, const float* __restrict__ w3,
        const float* __restrict__ b3, float* __restrict__ out) {
    extern __shared__ char smem[];
    uint32_t* XB    = (uint32_t*)smem;                  // [CG][2048] packed bf16
    float*    Spart = (float*)(smem + LDS_XB_BYTES);    // [16][16] wave-partial row sums
    float*    eL    = Spart + 256;                      // [16][16] x[i][256w]
    float*    eR    = eL + 256;                         // [16][16] x[i][256w+255]
    float*    F_l   = eR + 256;                         // [16] x[i][0]
    float*    L_l   = F_l + CG;                         // [16] x[i][8191]
    float*    V     = L_l + CG;                         // [49] v0,v1,v2,cb

    const int g    = blockIdx.x;
    const int wave = threadIdx.x >> 6;
    const int lane = threadIdx.x & 63;
    const size_t rowbase = (size_t)g * CG * LLEN;
    const int cA   = 256 * wave + 4 * lane;             // reg-half col
    const int cB   = 4096 + cA;                         // LDS-half col
    const int bidx = 128 * wave + 2 * lane;             // u32 index into XB row

    // ---------------- phase 1: load, row-sum, pack (regs + LDS) ----------------
    uint2 xA[CG];
    #pragma unroll
    for (int i = 0; i < CG; ++i) {
        const float* rp = x + rowbase + (size_t)i * LLEN;
        float4 a = *reinterpret_cast<const float4*>(rp + cA);
        float4 b = *reinterpret_cast<const float4*>(rp + cB);
        float s = ((a.x + a.y) + (a.z + a.w)) + ((b.x + b.y) + (b.z + b.w));
        #pragma unroll
        for (int off = 32; off; off >>= 1) s += __shfl_xor(s, off, 64);
        if (lane == 0) Spart[wave * CG + i] = s;        // static index only
        xA[i].x = packbf(a.x, a.y);
        xA[i].y = packbf(a.z, a.w);
        *reinterpret_cast<uint2*>(&XB[i * XB_U32 + bidx]) =
            make_uint2(packbf(b.x, b.y), packbf(b.z, b.w));
        if (lane == 0)  eL[wave * CG + i] = a.x;
        if (lane == 63) eR[wave * CG + i] = a.w;
        if (wave == 0  && lane == 0)  F_l[i] = a.x;
        if (wave == 15 && lane == 63) L_l[i] = b.w;
    }
    __syncthreads();

    // ---------------- prep: softmax -> collapsed taps (wave 0) ----------------
    if (wave == 0) {
        const int i = lane & 15;
        float S = 0.f;
        #pragma unroll
        for (int w = 0; w < CG; ++w) S += Spart[w * CG + i];
        float Fv = F_l[i], Lv = L_l[i];
        const float invL = 1.0f / (float)LLEN;
        float s1 = 0.f, s2 = 0.f;
        #pragma unroll
        for (int k = 0; k < CG; ++k) {
            float Sk = __shfl(S,  k, 16);
            float Fk = __shfl(Fv, k, 16);
            float Lk = __shfl(Lv, k, 16);
            s1 += w1[i * CG + k] * Sk;
            const float* w = &w3[(i * CG + k) * 3];
            s2 += w[0] * (Sk - Lk) + w[1] * Sk + w[2] * (Sk - Fk);
        }
        float m1 = s1 * invL + b1[i];
        float m2 = s2 * invL + b3[i];

        float mx1 = m1, mx2 = m2;
        #pragma unroll
        for (int off = 8; off; off >>= 1) {
            mx1 = fmaxf(mx1, __shfl_xor(mx1, off, 16));
            mx2 = fmaxf(mx2, __shfl_xor(mx2, off, 16));
        }
        float e1 = __expf(m1 - mx1), e2 = __expf(m2 - mx2);
        float d1 = e1, d2 = e2;
        #pragma unroll
        for (int off = 8; off; off >>= 1) {
            d1 += __shfl_xor(d1, off, 16);
            d2 += __shfl_xor(d2, off, 16);
        }
        float a1 = e1 / d1, a2 = e2 / d2;

        float cb = a1 * b3[i] + a2 * b1[i];
        #pragma unroll
        for (int off = 8; off; off >>= 1) cb += __shfl_xor(cb, off, 16);

        float v0 = 0.f, v1v = 0.f, v2 = 0.f;
        #pragma unroll
        for (int k = 0; k < CG; ++k) {
            float a1k = __shfl(a1, k, 16);
            float a2k = __shfl(a2, k, 16);
            const float* w = &w3[(k * CG + i) * 3];
            v0  += a1k * w[0];
            v1v += a1k * w[1] + a2k * w1[k * CG + i];
            v2  += a1k * w[2];
        }
        if (lane < 16) {
            V[i]      = v0;
            V[16 + i] = v1v;
            V[32 + i] = v2;
            if (lane == 0) V[48] = cb;
        }
    }
    __syncthreads();

    // ---------------- phase 2: 3-tap gate (regs + LDS), accumulate over rows ----
    const float cbv = V[48];
    float wA0 = cbv, wA1 = cbv, wA2 = cbv, wA3 = cbv;
    float wB0 = cbv, wB1 = cbv, wB2 = cbv, wB3 = cbv;
    #pragma unroll
    for (int i = 0; i < CG; ++i) {
        float a0 = unlo(xA[i].x), a1 = unhi(xA[i].x);
        float a2 = unlo(xA[i].y), a3 = unhi(xA[i].y);
        uint2 bw = *reinterpret_cast<const uint2*>(&XB[i * XB_U32 + bidx]);
        float b0 = unlo(bw.x), b1v = unhi(bw.x);
        float b2 = unlo(bw.y), b3v = unhi(bw.y);

        float pA = __shfl_up(a3, 1, 64);
        float nA = __shfl_down(a0, 1, 64);
        float pB = __shfl_up(b3v, 1, 64);
        float nB = __shfl_down(b0, 1, 64);
        if (lane == 0)  pA = wave ? eR[(wave - 1) * CG + i] : 0.f;
        if (lane == 63) nA = (wave < 15) ? eL[(wave + 1) * CG + i]
                                         : unlo(XB[i * XB_U32]);
        if (lane == 0)  pB = wave ? unhi(XB[i * XB_U32 + 128 * wave - 1])
                                  : eR[15 * CG + i];
        if (lane == 63) nB = (wave < 15) ? unlo(XB[i * XB_U32 + 128 * wave + 128])
                                         : 0.f;

        const float v0 = V[i], v1c = V[16 + i], v2c = V[32 + i];
        wA0 += v0 * pA  + v1c * a0  + v2c * a1;
        wA1 += v0 * a0  + v1c * a1  + v2c * a2;
        wA2 += v0 * a1  + v1c * a2  + v2c * a3;
        wA3 += v0 * a2  + v1c * a3  + v2c * nA;
        wB0 += v0 * pB  + v1c * b0  + v2c * b1v;
        wB1 += v0 * b0  + v1c * b1v + v2c * b2;
        wB2 += v0 * b1v + v1c * b2  + v2c * b3v;
        wB3 += v0 * b2  + v1c * b3v + v2c * nB;
    }
    const float sA0 = 1.f / (1.f + __expf(-wA0));
    const float sA1 = 1.f / (1.f + __expf(-wA1));
    const float sA2 = 1.f / (1.f + __expf(-wA2));
    const float sA3 = 1.f / (1.f + __expf(-wA3));
    const float sB0 = 1.f / (1.f + __expf(-wB0));
    const float sB1 = 1.f / (1.f + __expf(-wB1));
    const float sB2 = 1.f / (1.f + __expf(-wB2));
    const float sB3 = 1.f / (1.f + __expf(-wB3));

    #pragma unroll
    for (int i = 0; i < CG; ++i) {
        float* rp = out + rowbase + (size_t)i * LLEN;
        uint2 bw = *reinterpret_cast<const uint2*>(&XB[i * XB_U32 + bidx]);
        f32x4 oa = { unlo(xA[i].x) * sA0, unhi(xA[i].x) * sA1,
                     unlo(xA[i].y) * sA2, unhi(xA[i].y) * sA3 };
        f32x4 ob = { unlo(bw.x) * sB0, unhi(bw.x) * sB1,
                     unlo(bw.y) * sB2, unhi(bw.y) * sB3 };
        *reinterpret_cast<f32x4*>(rp + cA) = oa;
        *reinterpret_cast<f32x4*>(rp + cB) = ob;
    }
}

extern "C" void kernel_launch(void* const* d_in, const int* in_sizes, int n_in,
                              void* d_out, int out_size, void* d_ws, size_t ws_size,
                              hipStream_t stream) {
    const float* x  = (const float*)d_in[0];
    const float* w1 = (const float*)d_in[1];
    const float* b1 = (const float*)d_in[2];
    const float* w3 = (const float*)d_in[3];
    const float* b3 = (const float*)d_in[4];
    float* out = (float*)d_out;

    // Allow >64 KiB dynamic LDS (host-side, not stream-ordered: graph-safe).
    (void)hipFuncSetAttribute((const void*)fused_kernel,
                              hipFuncAttributeMaxDynamicSharedMemorySize, LDS_TOTAL);
    fused_kernel<<<NG, 1024, LDS_TOTAL, stream>>>(x, w1, b1, w3, b3, out);
}